// Round 5
// baseline (759.099 us; speedup 1.0000x reference)
//
#include <hip/hip_runtime.h>
#include <hip/hip_bf16.h>

using bf16 = __hip_bfloat16;
typedef __attribute__((ext_vector_type(8))) short short8;   // 8 bf16 (4 VGPR)
typedef __attribute__((ext_vector_type(4))) short short4v;  // 4 bf16 (8 B)
typedef __attribute__((ext_vector_type(4))) float f32x4;

constexpr int BATCH = 32;
constexpr int INC = 3;
constexpr int OC = 64;
constexpr int HH = 64;
constexpr int WW = 64;
constexpr int KK = 5;
constexpr int HP = 32;
constexpr int WP = 32;
constexpr int NL = 16;
constexpr int LW = 128;
constexpr int OW = 100;

__device__ __forceinline__ short f2bs(float v) {
  bf16 h = __float2bfloat16(v);
  return *(short*)&h;
}

// 16B zero page: per-lane global source for halo/pad lanes of global_load_lds.
// Device globals are zero-initialized at module load.
__device__ alignas(16) short zero16[16];

// ---------------- routing scores (partial): conv(x, node_filter) -> 16-row-group max ------
// grid: 4 depths * 32 batch * 4 row-groups = 512 blocks, 256 threads
__global__ __launch_bounds__(256) void k_scores(
    const float* __restrict__ x, const float* __restrict__ nw,
    float* __restrict__ scores_p) {
  int bid = blockIdx.x;
  int d = bid & 3;
  int b = (bid >> 2) & 31;
  int g = bid >> 7;  // 0..3: rows 16g..16g+15
  int f = (2 << d) - 2;  // node filter index used at depth d: 0,2,6,14
  __shared__ float wsm[75];
  __shared__ float red[256];
  int t = threadIdx.x;
  if (t < 75) wsm[t] = nw[f * 75 + t];
  __syncthreads();
  float m = -3.0e38f;
  for (int p = g * 1024 + t; p < (g + 1) * 1024; p += 256) {
    int y = p >> 6, xx = p & 63;
    float s = 0.f;
    for (int ic = 0; ic < INC; ic++) {
      for (int ky = 0; ky < KK; ky++) {
        int yy = y + ky - 2;
        if (yy < 0 || yy >= HH) continue;
        const float* xr = x + ((b * INC + ic) * HH + yy) * WW;
        const float* wr = &wsm[(ic * KK + ky) * KK];
        for (int kx = 0; kx < KK; kx++) {
          int xc = xx + kx - 2;
          if (xc < 0 || xc >= WW) continue;
          s = fmaf(xr[xc], wr[kx], s);
        }
      }
    }
    m = fmaxf(m, s);
  }
  red[t] = m;
  __syncthreads();
  for (int s2 = 128; s2 > 0; s2 >>= 1) {
    if (t < s2) red[t] = fmaxf(red[t], red[t + s2]);
    __syncthreads();
  }
  if (t == 0) scores_p[(d * BATCH + b) * 4 + g] = red[0];
}

// ---------------- soft-routing mixture over the binary tree (folds 4 partial maxes) -------
__global__ void k_mix(const float* __restrict__ scores_p,
                      const float* __restrict__ nb, float* __restrict__ mix) {
  int t = threadIdx.x;
  int b = t >> 4, l = t & 15;
  float m = 1.f;
#pragma unroll
  for (int d = 0; d < 4; d++) {
    const float* sp = scores_p + (d * BATCH + b) * 4;
    float sc = fmaxf(fmaxf(sp[0], sp[1]), fmaxf(sp[2], sp[3]));
    int j = l >> (3 - d);
    int i = j >> 1;
    int bit = j & 1;
    float z = sc + nb[(1 << d) - 1 + i];
    float be = 1.f / (1.f + expf(-z));
    m *= bit ? be : (1.f - be);
  }
  mix[b * NL + l] = m;
}

// ---------------- merged weight prep ----------------
__global__ __launch_bounds__(256) void k_prep(
    const float* __restrict__ cw1, const float* __restrict__ cw2,
    short* __restrict__ wA, short* __restrict__ wT) {
  int idx = blockIdx.x * 256 + threadIdx.x;
  if (idx < 98304) {
    int k = idx % 96;
    int rem = idx / 96;  // l*64 + oc
    float v = (k < 75) ? cw1[(size_t)rem * 75 + k] : 0.f;
    wA[(size_t)rem * 96 + k] = f2bs(v);
  } else {
    int i2 = idx - 98304;  // < 204800
    int icq = i2 & 7;
    int oc = (i2 >> 3) & 63;
    int rem = i2 >> 9;  // l*25 + tap
    short8 v;
#pragma unroll
    for (int j = 0; j < 8; j++) {
      int ic = icq * 8 + j;
      int l = rem / 25, tap = rem % 25;
      v[j] = f2bs(cw2[((size_t)(l * OC + oc) * OC + ic) * 25 + tap]);
    }
    *(short8*)(wT + ((size_t)rem * OC + oc) * OC + icq * 8) = v;
  }
}

// ---------------- conv1 via im2col + MFMA + in-register maxpool/relu -> h1t ----------------
// (R8/R12 version verbatim — known-good on hardware)
__device__ __forceinline__ int slotbase(int col) {
  return col * 104 + 8 * ((-(col >> 1)) & 7);
}

__global__ __launch_bounds__(256) void k_conv1m(
    const float* __restrict__ x, const short* __restrict__ wA,
    short* __restrict__ h1t) {
  constexpr int BSZ = 64 * 104 + 64;
  constexpr int OTS = 72;
  __shared__ alignas(16) short Bm[2 * BSZ];
  __shared__ alignas(16) short ot[32 * OTS];
  int bid = blockIdx.x;
  int py = bid & 31;
  int b = bid >> 5;
  int t = threadIdx.x;
  int w = t >> 6, lane = t & 63;
  int n = lane & 15, q = lane >> 4;

  for (int i = t; i < BSZ; i += 256) ((int*)Bm)[i] = 0;
  __syncthreads();
  for (int i = t; i < 1200; i += 256) {
    int cg = i & 7;
    int kk = (i >> 3) % 75;
    int dy = (i >> 3) / 75;
    int ic = kk / 25, r25 = kk % 25;
    int ky = r25 / 5, kx = r25 % 5;
    int y = 2 * py + dy + ky - 2;
    const float* xr = x + ((size_t)(b * INC + ic) * HH + y) * WW;
    short* dst = Bm + dy * BSZ;
#pragma unroll
    for (int c8 = 0; c8 < 8; c8++) {
      int c = cg * 8 + c8;
      int cx = c + kx - 2;
      float v = 0.f;
      if (y >= 0 && y < HH && cx >= 0 && cx < WW) v = xr[cx];
      dst[slotbase(c) + kk] = f2bs(v);
    }
  }
  __syncthreads();

  short8 Acur[3], Anx[3];
#pragma unroll
  for (int ks = 0; ks < 3; ks++)
    Anx[ks] = *(const short8*)(wA + ((size_t)(w * 16 + n) * 96) + ks * 32 + q * 8);

  for (int l = 0; l < NL; l++) {
#pragma unroll
    for (int ks = 0; ks < 3; ks++) Acur[ks] = Anx[ks];
    if (l < NL - 1) {
#pragma unroll
      for (int ks = 0; ks < 3; ks++)
        Anx[ks] = *(const short8*)(wA + ((size_t)((l + 1) * OC + w * 16 + n) * 96) +
                                   ks * 32 + q * 8);
    }
    f32x4 acc[2][2][2];  // [dy][dx][half]
#pragma unroll
    for (int dy = 0; dy < 2; dy++)
#pragma unroll
      for (int dx = 0; dx < 2; dx++)
#pragma unroll
        for (int h = 0; h < 2; h++) acc[dy][dx][h] = f32x4{0.f, 0.f, 0.f, 0.f};

#pragma unroll
    for (int dy = 0; dy < 2; dy++)
#pragma unroll
      for (int dx = 0; dx < 2; dx++)
#pragma unroll
        for (int h = 0; h < 2; h++) {
          int col = 2 * (h * 16 + n) + dx;
          const short* bp = Bm + dy * BSZ + slotbase(col);
#pragma unroll
          for (int ks = 0; ks < 3; ks++) {
            short8 Bf = *(const short8*)(bp + ks * 32 + q * 8);
            acc[dy][dx][h] = __builtin_amdgcn_mfma_f32_16x16x32_bf16(
                Acur[ks], Bf, acc[dy][dx][h], 0, 0, 0);
          }
        }

#pragma unroll
    for (int h = 0; h < 2; h++) {
      short4v sv;
#pragma unroll
      for (int r = 0; r < 4; r++) {
        float v = fmaxf(fmaxf(acc[0][0][h][r], acc[0][1][h][r]),
                        fmaxf(acc[1][0][h][r], acc[1][1][h][r]));
        sv[r] = f2bs(fmaxf(v, 0.f));
      }
      *(short4v*)(&ot[(h * 16 + n) * OTS + w * 16 + q * 4]) = sv;
    }
    __syncthreads();
    {
      int px = t >> 3, seg = t & 7;
      short8 v = *(const short8*)(&ot[px * OTS + seg * 8]);
      *(short8*)(h1t + ((size_t)(l * BATCH + b) * (HP * WP) + py * WP + px) * OC +
                 seg * 8) = v;
    }
    __syncthreads();
  }
}

// ---------------- conv2 via MFMA implicit GEMM + spatial max -> pfeat ----------------
// R17: dy-fold, col-half-split register allocation. Per (chunk, dx, ch):
// bulk-read the wave's 8 slab-row B-fragments for col-half ch ONCE (32 VGPR live),
// then loop dy (unrolled): load 4 A-frags (16 VGPR), fire 16 MFMAs into
// acc[oct][rt*2+ch]. Same total B-read count as R16 (80/wave/chunk, 2.5x below
// baseline) but half the held-B registers -> inner live set ~80 arch VGPRs,
// fits the 128 arch cap alongside 128 acc in the unified file (R15/R16 spilled:
// 37/33 MB scratch). A-loads double (L2-resident wT: cheap).
// dx and ch loops are unroll-1 ON PURPOSE: full unroll reconstructs R16's
// register blow-up.
__global__ __launch_bounds__(256, 2) void k_conv2m(
    const short* __restrict__ h1t, const short* __restrict__ wT,
    float* __restrict__ pfeat) {
  constexpr int CS2 = 32;          // shorts per col slot (64 B, no pad: linear)
  constexpr int RS2 = 36 * CS2;    // 1152 shorts = 2304 B per slab row
  __shared__ alignas(16) short hs[3072 * 8];  // 49152 B (20*2304=46080 used + pad)
  __shared__ alignas(16) float sred[4][64];
  int bid = blockIdx.x;
  int half = bid & 1;
  int b = (bid >> 1) & 31;
  int l = bid >> 6;
  int t = threadIdx.x;
  int w = t >> 6, lane = t & 63;
  int n = lane & 15, q = lane >> 4;
  int y0 = half * 16;
  const short* hg = h1t + (size_t)(l * BATCH + b) * (HP * WP) * OC;
  const short* wbase = wT + (size_t)l * 25 * OC * OC;

  f32x4 acc[4][8];  // [octile][pxt = rt*2 + ch], rt = local out row 0..3
#pragma unroll
  for (int i = 0; i < 4; i++)
#pragma unroll
    for (int j = 0; j < 8; j++) acc[i][j] = f32x4{0.f, 0.f, 0.f, 0.f};

  for (int chunk = 0; chunk < 2; chunk++) {
    __syncthreads();  // protect hs from previous chunk's readers
    // stage: 12 uniform iters x 256 thr = 3072 x 16B (2880 real + pad -> zero page)
#pragma unroll
    for (int i = 0; i < 12; i++) {
      int idx = i * 256 + t;            // 0..3071
      int icq = idx & 3;
      int cc = (idx >> 2) % 36;
      int r = (idx >> 2) / 36;          // 0..21 (r>=20 is pad)
      int y = y0 - 2 + r, xx = cc - 2;
      const short* gp = zero16;
      if (r < 20 && y >= 0 && y < HP && xx >= 0 && xx < WP)
        gp = hg + (y * WP + xx) * OC + chunk * 32 + icq * 8;
      __builtin_amdgcn_global_load_lds(
          (const __attribute__((address_space(1))) void*)gp,
          (__attribute__((address_space(3))) void*)&hs[idx * 8], 16, 0, 0);
    }
    __syncthreads();  // compiler drains vmcnt before the barrier

    const short* hb0 = &hs[(4 * w) * RS2 + n * CS2 + q * 8];
    const short* an = wbase + (size_t)chunk * 32 + (size_t)n * OC + q * 8;

#pragma unroll 1
    for (int dx = 0; dx < 5; dx++) {
      const short* hp = hb0 + dx * CS2;
#pragma unroll 1
      for (int ch = 0; ch < 2; ch++) {
        // bulk-read the wave's 8 B-fragments for this (chunk, dx, ch)
        short8 Bf[8];
#pragma unroll
        for (int j = 0; j < 8; j++)
          Bf[j] = *(const short8*)(hp + j * RS2 + ch * 16 * CS2);
#pragma unroll
        for (int dy = 0; dy < 5; dy++) {
          short8 Af[4];
#pragma unroll
          for (int oct = 0; oct < 4; oct++)
            Af[oct] = *(const short8*)(
                an + ((size_t)((dy * 5 + dx) * OC + oct * 16)) * OC);
#pragma unroll
          for (int rt = 0; rt < 4; rt++) {
            int j = rt + dy;  // slab row 4w + j feeds out row 4w + rt via tap dy
#pragma unroll
            for (int oct = 0; oct < 4; oct++)
              acc[oct][rt * 2 + ch] = __builtin_amdgcn_mfma_f32_16x16x32_bf16(
                  Af[oct], Bf[j], acc[oct][rt * 2 + ch], 0, 0, 0);
          }
        }
      }
    }
  }

  // epilogue: max over this wave's 128 px; D layout: col(px)=lane&15, row(oc)=q*4+reg
#pragma unroll
  for (int oct = 0; oct < 4; oct++) {
    f32x4 m = acc[oct][0];
#pragma unroll
    for (int pxt = 1; pxt < 8; pxt++)
#pragma unroll
      for (int r = 0; r < 4; r++) m[r] = fmaxf(m[r], acc[oct][pxt][r]);
#pragma unroll
    for (int mask = 1; mask <= 8; mask <<= 1)
#pragma unroll
      for (int r = 0; r < 4; r++) m[r] = fmaxf(m[r], __shfl_xor(m[r], mask, 64));
    if (n == 0) *(f32x4*)&sred[w][oct * 16 + q * 4] = m;
  }
  __syncthreads();
  if (t < 64) {
    float m = fmaxf(fmaxf(sred[0][t], sred[1][t]), fmaxf(sred[2][t], sred[3][t]));
    pfeat[((size_t)(l * BATCH + b) * 2 + half) * OC + t] = m;
  }
}

// ---------------- per-leaf 2-layer MLP; folds half-max + relu ----------------
__global__ __launch_bounds__(128) void k_mlp(
    const float* __restrict__ pfeat, const float* __restrict__ w1s,
    const float* __restrict__ b1s, const float* __restrict__ w2s,
    const float* __restrict__ b2s, float* __restrict__ logits) {
  __shared__ float fs[OC];
  __shared__ float hid[LW];
  int bid = blockIdx.x;
  int b = bid & 31;
  int l = bid >> 5;
  int t = threadIdx.x;
  if (t < OC) {
    const float* pf = pfeat + (size_t)(l * BATCH + b) * 2 * OC;
    fs[t] = fmaxf(fmaxf(pf[t], pf[OC + t]), 0.f);  // relu(global max)
  }
  __syncthreads();
  float h = b1s[l * LW + t];
  for (int c = 0; c < OC; c++)
    h = fmaf(fs[c], w1s[(l * OC + c) * LW + t], h);
  hid[t] = h;
  __syncthreads();
  if (t < OW) {
    float o = b2s[l * OW + t];
    for (int j = 0; j < LW; j++)
      o = fmaf(hid[j], w2s[(l * LW + j) * OW + t], o);
    logits[(size_t)(l * BATCH + b) * OW + t] = o;
  }
}

// ---------------- out[b,o] = sum_l mix[b,l] * logits[l,b,o]  (fp32 out) ----------------
__global__ __launch_bounds__(256) void k_combine(
    const float* __restrict__ logits, const float* __restrict__ mix,
    float* __restrict__ out) {
  int idx = blockIdx.x * 256 + threadIdx.x;
  if (idx >= BATCH * OW) return;
  int b = idx / OW, o = idx - b * OW;
  float s = 0.f;
#pragma unroll
  for (int l = 0; l < NL; l++)
    s = fmaf(mix[b * NL + l], logits[((size_t)l * BATCH + b) * OW + o], s);
  out[idx] = s;
}

extern "C" void kernel_launch(void* const* d_in, const int* in_sizes, int n_in,
                              void* d_out, int out_size, void* d_ws, size_t ws_size,
                              hipStream_t stream) {
  const float* x   = (const float*)d_in[0];
  const float* nw  = (const float*)d_in[1];
  const float* nb  = (const float*)d_in[2];
  const float* cw1 = (const float*)d_in[3];
  const float* cw2 = (const float*)d_in[4];
  const float* w1s = (const float*)d_in[5];
  const float* b1s = (const float*)d_in[6];
  const float* w2s = (const float*)d_in[7];
  const float* b2s = (const float*)d_in[8];
  float* out = (float*)d_out;

  char* ws = (char*)d_ws;
  short* h1t = (short*)ws;  // [l,b][px 1024][ic 64] bf16 = 67.1 MB
  size_t off = (size_t)NL * BATCH * HP * WP * OC * sizeof(short);
  short* wT = (short*)(ws + off); off += (size_t)NL * 25 * OC * OC * sizeof(short);
  short* wA = (short*)(ws + off); off += (size_t)NL * OC * 96 * sizeof(short);
  float* scores_p = (float*)(ws + off); off += 4 * BATCH * 4 * sizeof(float);
  float* mixp   = (float*)(ws + off); off += BATCH * NL * sizeof(float);
  float* pfeat  = (float*)(ws + off); off += (size_t)NL * BATCH * 2 * OC * sizeof(float);
  float* logits = (float*)(ws + off); off += (size_t)NL * BATCH * OW * sizeof(float);
  (void)ws_size; (void)in_sizes; (void)n_in; (void)out_size;

  k_scores<<<4 * BATCH * 4, 256, 0, stream>>>(x, nw, scores_p);
  k_mix<<<1, BATCH * NL, 0, stream>>>(scores_p, nb, mixp);
  k_prep<<<(98304 + 204800) / 256, 256, 0, stream>>>(cw1, cw2, wA, wT);
  k_conv1m<<<BATCH * 32, 256, 0, stream>>>(x, wA, h1t);
  k_conv2m<<<NL * BATCH * 2, 256, 0, stream>>>(h1t, wT, pfeat);
  k_mlp<<<NL * BATCH, 128, 0, stream>>>(pfeat, w1s, b1s, w2s, b2s, logits);
  k_combine<<<(BATCH * OW + 255) / 256, 256, 0, stream>>>(logits, mixp, out);
}

// Round 6
// 223.861 us; speedup vs baseline: 3.3909x; 3.3909x over previous
//
#include <hip/hip_runtime.h>
#include <hip/hip_bf16.h>

using bf16 = __hip_bfloat16;
typedef __attribute__((ext_vector_type(8))) short short8;   // 8 bf16 (4 VGPR)
typedef __attribute__((ext_vector_type(4))) short short4v;  // 4 bf16 (8 B)
typedef __attribute__((ext_vector_type(4))) float f32x4;
typedef __attribute__((ext_vector_type(16))) float f32x16;

constexpr int BATCH = 32;
constexpr int INC = 3;
constexpr int OC = 64;
constexpr int HH = 64;
constexpr int WW = 64;
constexpr int KK = 5;
constexpr int HP = 32;
constexpr int WP = 32;
constexpr int NL = 16;
constexpr int LW = 128;
constexpr int OW = 100;

__device__ __forceinline__ short f2bs(float v) {
  bf16 h = __float2bfloat16(v);
  return *(short*)&h;
}

// 16B zero page: per-lane global source for halo/pad lanes of global_load_lds.
__device__ alignas(16) short zero16[16];

// ---------------- routing scores (partial): conv(x, node_filter) -> 16-row-group max ------
__global__ __launch_bounds__(256) void k_scores(
    const float* __restrict__ x, const float* __restrict__ nw,
    float* __restrict__ scores_p) {
  int bid = blockIdx.x;
  int d = bid & 3;
  int b = (bid >> 2) & 31;
  int g = bid >> 7;  // 0..3: rows 16g..16g+15
  int f = (2 << d) - 2;  // node filter index used at depth d: 0,2,6,14
  __shared__ float wsm[75];
  __shared__ float red[256];
  int t = threadIdx.x;
  if (t < 75) wsm[t] = nw[f * 75 + t];
  __syncthreads();
  float m = -3.0e38f;
  for (int p = g * 1024 + t; p < (g + 1) * 1024; p += 256) {
    int y = p >> 6, xx = p & 63;
    float s = 0.f;
    for (int ic = 0; ic < INC; ic++) {
      for (int ky = 0; ky < KK; ky++) {
        int yy = y + ky - 2;
        if (yy < 0 || yy >= HH) continue;
        const float* xr = x + ((b * INC + ic) * HH + yy) * WW;
        const float* wr = &wsm[(ic * KK + ky) * KK];
        for (int kx = 0; kx < KK; kx++) {
          int xc = xx + kx - 2;
          if (xc < 0 || xc >= WW) continue;
          s = fmaf(xr[xc], wr[kx], s);
        }
      }
    }
    m = fmaxf(m, s);
  }
  red[t] = m;
  __syncthreads();
  for (int s2 = 128; s2 > 0; s2 >>= 1) {
    if (t < s2) red[t] = fmaxf(red[t], red[t + s2]);
    __syncthreads();
  }
  if (t == 0) scores_p[(d * BATCH + b) * 4 + g] = red[0];
}

// ---------------- soft-routing mixture over the binary tree ----------------
__global__ void k_mix(const float* __restrict__ scores_p,
                      const float* __restrict__ nb, float* __restrict__ mix) {
  int t = threadIdx.x;
  int b = t >> 4, l = t & 15;
  float m = 1.f;
#pragma unroll
  for (int d = 0; d < 4; d++) {
    const float* sp = scores_p + (d * BATCH + b) * 4;
    float sc = fmaxf(fmaxf(sp[0], sp[1]), fmaxf(sp[2], sp[3]));
    int j = l >> (3 - d);
    int i = j >> 1;
    int bit = j & 1;
    float z = sc + nb[(1 << d) - 1 + i];
    float be = 1.f / (1.f + expf(-z));
    m *= bit ? be : (1.f - be);
  }
  mix[b * NL + l] = m;
}

// ---------------- merged weight prep ----------------
__global__ __launch_bounds__(256) void k_prep(
    const float* __restrict__ cw1, const float* __restrict__ cw2,
    short* __restrict__ wA, short* __restrict__ wT) {
  int idx = blockIdx.x * 256 + threadIdx.x;
  if (idx < 98304) {
    int k = idx % 96;
    int rem = idx / 96;  // l*64 + oc
    float v = (k < 75) ? cw1[(size_t)rem * 75 + k] : 0.f;
    wA[(size_t)rem * 96 + k] = f2bs(v);
  } else {
    int i2 = idx - 98304;  // < 204800
    int icq = i2 & 7;
    int oc = (i2 >> 3) & 63;
    int rem = i2 >> 9;  // l*25 + tap
    short8 v;
#pragma unroll
    for (int j = 0; j < 8; j++) {
      int ic = icq * 8 + j;
      int l = rem / 25, tap = rem % 25;
      v[j] = f2bs(cw2[((size_t)(l * OC + oc) * OC + ic) * 25 + tap]);
    }
    *(short8*)(wT + ((size_t)rem * OC + oc) * OC + icq * 8) = v;
  }
}

// ---------------- conv1 via im2col + MFMA + in-register maxpool/relu -> h1t ----------------
// (R8/R12 version verbatim — known-good on hardware)
__device__ __forceinline__ int slotbase(int col) {
  return col * 104 + 8 * ((-(col >> 1)) & 7);
}

__global__ __launch_bounds__(256) void k_conv1m(
    const float* __restrict__ x, const short* __restrict__ wA,
    short* __restrict__ h1t) {
  constexpr int BSZ = 64 * 104 + 64;
  constexpr int OTS = 72;
  __shared__ alignas(16) short Bm[2 * BSZ];
  __shared__ alignas(16) short ot[32 * OTS];
  int bid = blockIdx.x;
  int py = bid & 31;
  int b = bid >> 5;
  int t = threadIdx.x;
  int w = t >> 6, lane = t & 63;
  int n = lane & 15, q = lane >> 4;

  for (int i = t; i < BSZ; i += 256) ((int*)Bm)[i] = 0;
  __syncthreads();
  for (int i = t; i < 1200; i += 256) {
    int cg = i & 7;
    int kk = (i >> 3) % 75;
    int dy = (i >> 3) / 75;
    int ic = kk / 25, r25 = kk % 25;
    int ky = r25 / 5, kx = r25 % 5;
    int y = 2 * py + dy + ky - 2;
    const float* xr = x + ((size_t)(b * INC + ic) * HH + y) * WW;
    short* dst = Bm + dy * BSZ;
#pragma unroll
    for (int c8 = 0; c8 < 8; c8++) {
      int c = cg * 8 + c8;
      int cx = c + kx - 2;
      float v = 0.f;
      if (y >= 0 && y < HH && cx >= 0 && cx < WW) v = xr[cx];
      dst[slotbase(c) + kk] = f2bs(v);
    }
  }
  __syncthreads();

  short8 Acur[3], Anx[3];
#pragma unroll
  for (int ks = 0; ks < 3; ks++)
    Anx[ks] = *(const short8*)(wA + ((size_t)(w * 16 + n) * 96) + ks * 32 + q * 8);

  for (int l = 0; l < NL; l++) {
#pragma unroll
    for (int ks = 0; ks < 3; ks++) Acur[ks] = Anx[ks];
    if (l < NL - 1) {
#pragma unroll
      for (int ks = 0; ks < 3; ks++)
        Anx[ks] = *(const short8*)(wA + ((size_t)((l + 1) * OC + w * 16 + n) * 96) +
                                   ks * 32 + q * 8);
    }
    f32x4 acc[2][2][2];  // [dy][dx][half]
#pragma unroll
    for (int dy = 0; dy < 2; dy++)
#pragma unroll
      for (int dx = 0; dx < 2; dx++)
#pragma unroll
        for (int h = 0; h < 2; h++) acc[dy][dx][h] = f32x4{0.f, 0.f, 0.f, 0.f};

#pragma unroll
    for (int dy = 0; dy < 2; dy++)
#pragma unroll
      for (int dx = 0; dx < 2; dx++)
#pragma unroll
        for (int h = 0; h < 2; h++) {
          int col = 2 * (h * 16 + n) + dx;
          const short* bp = Bm + dy * BSZ + slotbase(col);
#pragma unroll
          for (int ks = 0; ks < 3; ks++) {
            short8 Bf = *(const short8*)(bp + ks * 32 + q * 8);
            acc[dy][dx][h] = __builtin_amdgcn_mfma_f32_16x16x32_bf16(
                Acur[ks], Bf, acc[dy][dx][h], 0, 0, 0);
          }
        }

#pragma unroll
    for (int h = 0; h < 2; h++) {
      short4v sv;
#pragma unroll
      for (int r = 0; r < 4; r++) {
        float v = fmaxf(fmaxf(acc[0][0][h][r], acc[0][1][h][r]),
                        fmaxf(acc[1][0][h][r], acc[1][1][h][r]));
        sv[r] = f2bs(fmaxf(v, 0.f));
      }
      *(short4v*)(&ot[(h * 16 + n) * OTS + w * 16 + q * 4]) = sv;
    }
    __syncthreads();
    {
      int px = t >> 3, seg = t & 7;
      short8 v = *(const short8*)(&ot[px * OTS + seg * 8]);
      *(short8*)(h1t + ((size_t)(l * BATCH + b) * (HP * WP) + py * WP + px) * OC +
                 seg * 8) = v;
    }
    __syncthreads();
  }
}

// ---------------- conv2: pipelined implicit GEMM, 32x32x16 MFMA, all-LDS compute ----------
// R18: block = 8 out rows x 32 cols x 32 oc (grid 4096, XCD-swizzled: 2 leaves/XCD).
// 4 ic16 chunks; per chunk: A (25 taps x 32 oc x 16 ic, 25.6 KB) staged into LDS once,
// B slab (12 r x 36 c x 16 ic, 14 KB) double-buffered with next-chunk staging issued
// BEFORE compute so HBM latency hides under 25 taps x 8 MFMA. No global loads in the
// tap loop -> no vmcnt ordering hazard, no A register pressure (acc = 32 VGPR only).
// LDS 54.3 KB -> 3 blocks/CU (12 waves). Raw s_barrier + explicit waitcnt (m201 pattern).
__global__ __launch_bounds__(256, 3) void k_conv2m(
    const short* __restrict__ h1t, const short* __restrict__ wT,
    float* __restrict__ pfeat) {
  // LDS granule = 16 B. Layout (shorts): [B0: 896g = 7168][B1: 896g][A: 1600g = 12800]
  __shared__ alignas(16) short hs[27136];  // 54,272 B
  int raw = blockIdx.x;
  int bid = (raw & 7) * 512 + (raw >> 3);  // XCD swizzle: 4096 % 8 == 0 (bijective)
  int och = bid & 1;
  int qtr = (bid >> 1) & 3;
  int b = (bid >> 3) & 31;
  int l = bid >> 8;
  int t = threadIdx.x;
  int w = t >> 6, lane = t & 63;
  int col = lane & 31, h = lane >> 5;
  int y0 = qtr * 8;
  const short* hg = h1t + (size_t)(l * BATCH + b) * (HP * WP) * OC;
  const short* wb = wT + (size_t)l * 25 * OC * OC + och * 32 * OC;

  // ---- precompute per-thread staging offsets (reused for all 4 chunks) ----
  int ofsB[4];
#pragma unroll
  for (int i = 0; i < 4; i++) {
    int g = i * 256 + t;        // granule 0..1023 (>=896 never issued)
    int hh = g & 1, s = g >> 1;
    int cc = s % 36, r = s / 36;
    int y = y0 - 2 + r, xx = cc - 2;
    bool ok = (r < 12) && (y >= 0) && (y < HP) && (xx >= 0) && (xx < WP);
    ofsB[i] = ok ? ((y * WP + xx) * OC + hh * 8) : -1;
  }
  int ofsA[7];
#pragma unroll
  for (int i = 0; i < 7; i++) {
    int g = i * 256 + t;        // granule; i==6 valid only for t<64 (g<1600)
    int hh = g & 1, s = g >> 1;
    int tap = s >> 5, oc = s & 31;
    ofsA[i] = (tap * OC + oc) * OC + hh * 8;
  }

#define STAGE_B(buf, chunk)                                                       \
  {                                                                               \
    _Pragma("unroll") for (int i = 0; i < 4; i++) {                               \
      if (i < 3 || t < 128) {                                                     \
        const short* gp = (ofsB[i] < 0) ? zero16 : (hg + ofsB[i] + (chunk)*16);   \
        __builtin_amdgcn_global_load_lds(                                         \
            (const __attribute__((address_space(1))) void*)gp,                    \
            (__attribute__((address_space(3))) void*)&hs[(buf)*7168 +             \
                                                         (i * 256 + t) * 8],      \
            16, 0, 0);                                                            \
      }                                                                           \
    }                                                                             \
  }
#define STAGE_A(chunk)                                                            \
  {                                                                               \
    _Pragma("unroll") for (int i = 0; i < 7; i++) {                               \
      if (i < 6 || t < 64) {                                                      \
        const short* gp = wb + ofsA[i] + (chunk)*16;                              \
        __builtin_amdgcn_global_load_lds(                                         \
            (const __attribute__((address_space(1))) void*)gp,                    \
            (__attribute__((address_space(3))) void*)&hs[14336 +                  \
                                                         (i * 256 + t) * 8],      \
            16, 0, 0);                                                            \
      }                                                                           \
    }                                                                             \
  }

  f32x16 acc0, acc1;
#pragma unroll
  for (int r = 0; r < 16; r++) { acc0[r] = 0.f; acc1[r] = 0.f; }

  int a_base = 14336 + col * 16 + h * 8;             // + tap*512
  int b_base = (2 * w * 36 + col) * 16 + h * 8;      // + buf*7168 + ((rt+dy)*36+dx)*16

  STAGE_B(0, 0);
  STAGE_A(0);
  asm volatile("s_waitcnt vmcnt(0)" ::: "memory");
  __builtin_amdgcn_s_barrier();

#pragma unroll 1
  for (int c = 0; c < 4; c++) {
    int cur = c & 1;
    if (c < 3) STAGE_B(cur ^ 1, c + 1);   // flies under the 25-tap compute below
    const short* Bb = hs + cur * 7168;
#pragma unroll
    for (int tap = 0; tap < 25; tap++) {
      int dy = tap / 5, dx = tap % 5;
      short8 Af = *(const short8*)(hs + a_base + tap * 512);
      short8 B0 = *(const short8*)(Bb + b_base + ((dy + 0) * 36 + dx) * 16);
      short8 B1 = *(const short8*)(Bb + b_base + ((dy + 1) * 36 + dx) * 16);
      acc0 = __builtin_amdgcn_mfma_f32_32x32x16_bf16(Af, B0, acc0, 0, 0, 0);
      acc1 = __builtin_amdgcn_mfma_f32_32x32x16_bf16(Af, B1, acc1, 0, 0, 0);
    }
    asm volatile("s_waitcnt vmcnt(0) lgkmcnt(0)" ::: "memory");
    __builtin_amdgcn_s_barrier();
    if (c < 3) {
      STAGE_A(c + 1);   // single A buffer: overwrite only after the barrier above
      asm volatile("s_waitcnt vmcnt(0)" ::: "memory");
      __builtin_amdgcn_s_barrier();
    }
  }
#undef STAGE_B
#undef STAGE_A

  // epilogue: max over this wave's 64 px; D layout (32x32): col=lane&31,
  // row = (reg&3) + 8*(reg>>2) + 4*(lane>>5)
  float* sred = (float*)hs;  // alias B0 region (dead after final barrier)
  float m[16];
#pragma unroll
  for (int r = 0; r < 16; r++) m[r] = fmaxf(acc0[r], acc1[r]);
#pragma unroll
  for (int mask = 1; mask <= 16; mask <<= 1)
#pragma unroll
    for (int r = 0; r < 16; r++) m[r] = fmaxf(m[r], __shfl_xor(m[r], mask, 64));
  if (col == 0) {
#pragma unroll
    for (int r = 0; r < 16; r++)
      sred[w * 32 + 4 * h + (r & 3) + 8 * (r >> 2)] = m[r];
  }
  __syncthreads();
  if (t < 32) {
    float mm = fmaxf(fmaxf(sred[t], sred[32 + t]), fmaxf(sred[64 + t], sred[96 + t]));
    pfeat[((size_t)(l * BATCH + b) * 8 + och * 4 + qtr) * 32 + t] = mm;
  }
}

// ---------------- per-leaf 2-layer MLP; folds 8 partial maxes + relu ----------------
__global__ __launch_bounds__(128) void k_mlp(
    const float* __restrict__ pfeat, const float* __restrict__ w1s,
    const float* __restrict__ b1s, const float* __restrict__ w2s,
    const float* __restrict__ b2s, float* __restrict__ logits) {
  __shared__ float fs[OC];
  __shared__ float hid[LW];
  int bid = blockIdx.x;
  int b = bid & 31;
  int l = bid >> 5;
  int t = threadIdx.x;
  if (t < OC) {
    const float* pf = pfeat + ((size_t)(l * BATCH + b) * 8 + (t >> 5) * 4) * 32 + (t & 31);
    float m = fmaxf(fmaxf(pf[0], pf[32]), fmaxf(pf[64], pf[96]));
    fs[t] = fmaxf(m, 0.f);  // relu(global max)
  }
  __syncthreads();
  float h = b1s[l * LW + t];
  for (int c = 0; c < OC; c++)
    h = fmaf(fs[c], w1s[(l * OC + c) * LW + t], h);
  hid[t] = h;
  __syncthreads();
  if (t < OW) {
    float o = b2s[l * OW + t];
    for (int j = 0; j < LW; j++)
      o = fmaf(hid[j], w2s[(l * LW + j) * OW + t], o);
    logits[(size_t)(l * BATCH + b) * OW + t] = o;
  }
}

// ---------------- out[b,o] = sum_l mix[b,l] * logits[l,b,o]  (fp32 out) ----------------
__global__ __launch_bounds__(256) void k_combine(
    const float* __restrict__ logits, const float* __restrict__ mix,
    float* __restrict__ out) {
  int idx = blockIdx.x * 256 + threadIdx.x;
  if (idx >= BATCH * OW) return;
  int b = idx / OW, o = idx - b * OW;
  float s = 0.f;
#pragma unroll
  for (int l = 0; l < NL; l++)
    s = fmaf(mix[b * NL + l], logits[((size_t)l * BATCH + b) * OW + o], s);
  out[idx] = s;
}

extern "C" void kernel_launch(void* const* d_in, const int* in_sizes, int n_in,
                              void* d_out, int out_size, void* d_ws, size_t ws_size,
                              hipStream_t stream) {
  const float* x   = (const float*)d_in[0];
  const float* nw  = (const float*)d_in[1];
  const float* nb  = (const float*)d_in[2];
  const float* cw1 = (const float*)d_in[3];
  const float* cw2 = (const float*)d_in[4];
  const float* w1s = (const float*)d_in[5];
  const float* b1s = (const float*)d_in[6];
  const float* w2s = (const float*)d_in[7];
  const float* b2s = (const float*)d_in[8];
  float* out = (float*)d_out;

  char* ws = (char*)d_ws;
  short* h1t = (short*)ws;  // [l,b][px 1024][ic 64] bf16 = 67.1 MB
  size_t off = (size_t)NL * BATCH * HP * WP * OC * sizeof(short);
  short* wT = (short*)(ws + off); off += (size_t)NL * 25 * OC * OC * sizeof(short);
  short* wA = (short*)(ws + off); off += (size_t)NL * OC * 96 * sizeof(short);
  float* scores_p = (float*)(ws + off); off += 4 * BATCH * 4 * sizeof(float);
  float* mixp   = (float*)(ws + off); off += BATCH * NL * sizeof(float);
  float* pfeat  = (float*)(ws + off); off += (size_t)NL * BATCH * 8 * 32 * sizeof(float);
  float* logits = (float*)(ws + off); off += (size_t)NL * BATCH * OW * sizeof(float);
  (void)ws_size; (void)in_sizes; (void)n_in; (void)out_size;

  k_scores<<<4 * BATCH * 4, 256, 0, stream>>>(x, nw, scores_p);
  k_mix<<<1, BATCH * NL, 0, stream>>>(scores_p, nb, mixp);
  k_prep<<<(98304 + 204800) / 256, 256, 0, stream>>>(cw1, cw2, wA, wT);
  k_conv1m<<<BATCH * 32, 256, 0, stream>>>(x, wA, h1t);
  k_conv2m<<<NL * BATCH * 4 * 2, 256, 0, stream>>>(h1t, wT, pfeat);
  k_mlp<<<NL * BATCH, 128, 0, stream>>>(pfeat, w1s, b1s, w2s, b2s, logits);
  k_combine<<<(BATCH * OW + 255) / 256, 256, 0, stream>>>(logits, mixp, out);
}

// Round 7
// 202.585 us; speedup vs baseline: 3.7471x; 1.1050x over previous
//
#include <hip/hip_runtime.h>
#include <hip/hip_bf16.h>

using bf16 = __hip_bfloat16;
typedef __attribute__((ext_vector_type(8))) short short8;   // 8 bf16 (4 VGPR)
typedef __attribute__((ext_vector_type(4))) short short4v;  // 4 bf16 (8 B)
typedef __attribute__((ext_vector_type(4))) float f32x4;

constexpr int BATCH = 32;
constexpr int INC = 3;
constexpr int OC = 64;
constexpr int HH = 64;
constexpr int WW = 64;
constexpr int KK = 5;
constexpr int HP = 32;
constexpr int WP = 32;
constexpr int NL = 16;
constexpr int LW = 128;
constexpr int OW = 100;

__device__ __forceinline__ short f2bs(float v) {
  bf16 h = __float2bfloat16(v);
  return *(short*)&h;
}

// 16B zero page: per-lane global source for halo/pad lanes of global_load_lds.
__device__ alignas(16) short zero16[16];

// ---------------- routing scores (partial): conv(x, node_filter) -> 16-row-group max ------
__global__ __launch_bounds__(256) void k_scores(
    const float* __restrict__ x, const float* __restrict__ nw,
    float* __restrict__ scores_p) {
  int bid = blockIdx.x;
  int d = bid & 3;
  int b = (bid >> 2) & 31;
  int g = bid >> 7;  // 0..3: rows 16g..16g+15
  int f = (2 << d) - 2;  // node filter index used at depth d: 0,2,6,14
  __shared__ float wsm[75];
  __shared__ float red[256];
  int t = threadIdx.x;
  if (t < 75) wsm[t] = nw[f * 75 + t];
  __syncthreads();
  float m = -3.0e38f;
  for (int p = g * 1024 + t; p < (g + 1) * 1024; p += 256) {
    int y = p >> 6, xx = p & 63;
    float s = 0.f;
    for (int ic = 0; ic < INC; ic++) {
      for (int ky = 0; ky < KK; ky++) {
        int yy = y + ky - 2;
        if (yy < 0 || yy >= HH) continue;
        const float* xr = x + ((b * INC + ic) * HH + yy) * WW;
        const float* wr = &wsm[(ic * KK + ky) * KK];
        for (int kx = 0; kx < KK; kx++) {
          int xc = xx + kx - 2;
          if (xc < 0 || xc >= WW) continue;
          s = fmaf(xr[xc], wr[kx], s);
        }
      }
    }
    m = fmaxf(m, s);
  }
  red[t] = m;
  __syncthreads();
  for (int s2 = 128; s2 > 0; s2 >>= 1) {
    if (t < s2) red[t] = fmaxf(red[t], red[t + s2]);
    __syncthreads();
  }
  if (t == 0) scores_p[(d * BATCH + b) * 4 + g] = red[0];
}

// ---------------- soft-routing mixture over the binary tree ----------------
__global__ void k_mix(const float* __restrict__ scores_p,
                      const float* __restrict__ nb, float* __restrict__ mix) {
  int t = threadIdx.x;
  int b = t >> 4, l = t & 15;
  float m = 1.f;
#pragma unroll
  for (int d = 0; d < 4; d++) {
    const float* sp = scores_p + (d * BATCH + b) * 4;
    float sc = fmaxf(fmaxf(sp[0], sp[1]), fmaxf(sp[2], sp[3]));
    int j = l >> (3 - d);
    int i = j >> 1;
    int bit = j & 1;
    float z = sc + nb[(1 << d) - 1 + i];
    float be = 1.f / (1.f + expf(-z));
    m *= bit ? be : (1.f - be);
  }
  mix[b * NL + l] = m;
}

// ---------------- merged weight prep ----------------
__global__ __launch_bounds__(256) void k_prep(
    const float* __restrict__ cw1, const float* __restrict__ cw2,
    short* __restrict__ wA, short* __restrict__ wT) {
  int idx = blockIdx.x * 256 + threadIdx.x;
  if (idx < 98304) {
    int k = idx % 96;
    int rem = idx / 96;  // l*64 + oc
    float v = (k < 75) ? cw1[(size_t)rem * 75 + k] : 0.f;
    wA[(size_t)rem * 96 + k] = f2bs(v);
  } else {
    int i2 = idx - 98304;  // < 204800
    int icq = i2 & 7;
    int oc = (i2 >> 3) & 63;
    int rem = i2 >> 9;  // l*25 + tap
    short8 v;
#pragma unroll
    for (int j = 0; j < 8; j++) {
      int ic = icq * 8 + j;
      int l = rem / 25, tap = rem % 25;
      v[j] = f2bs(cw2[((size_t)(l * OC + oc) * OC + ic) * 25 + tap]);
    }
    *(short8*)(wT + ((size_t)rem * OC + oc) * OC + icq * 8) = v;
  }
}

// ---------------- conv1 via im2col + MFMA + in-register maxpool/relu -> h1t ----------------
// (R8/R12 version verbatim — known-good on hardware)
__device__ __forceinline__ int slotbase(int col) {
  return col * 104 + 8 * ((-(col >> 1)) & 7);
}

__global__ __launch_bounds__(256) void k_conv1m(
    const float* __restrict__ x, const short* __restrict__ wA,
    short* __restrict__ h1t) {
  constexpr int BSZ = 64 * 104 + 64;
  constexpr int OTS = 72;
  __shared__ alignas(16) short Bm[2 * BSZ];
  __shared__ alignas(16) short ot[32 * OTS];
  int bid = blockIdx.x;
  int py = bid & 31;
  int b = bid >> 5;
  int t = threadIdx.x;
  int w = t >> 6, lane = t & 63;
  int n = lane & 15, q = lane >> 4;

  for (int i = t; i < BSZ; i += 256) ((int*)Bm)[i] = 0;
  __syncthreads();
  for (int i = t; i < 1200; i += 256) {
    int cg = i & 7;
    int kk = (i >> 3) % 75;
    int dy = (i >> 3) / 75;
    int ic = kk / 25, r25 = kk % 25;
    int ky = r25 / 5, kx = r25 % 5;
    int y = 2 * py + dy + ky - 2;
    const float* xr = x + ((size_t)(b * INC + ic) * HH + y) * WW;
    short* dst = Bm + dy * BSZ;
#pragma unroll
    for (int c8 = 0; c8 < 8; c8++) {
      int c = cg * 8 + c8;
      int cx = c + kx - 2;
      float v = 0.f;
      if (y >= 0 && y < HH && cx >= 0 && cx < WW) v = xr[cx];
      dst[slotbase(c) + kk] = f2bs(v);
    }
  }
  __syncthreads();

  short8 Acur[3], Anx[3];
#pragma unroll
  for (int ks = 0; ks < 3; ks++)
    Anx[ks] = *(const short8*)(wA + ((size_t)(w * 16 + n) * 96) + ks * 32 + q * 8);

  for (int l = 0; l < NL; l++) {
#pragma unroll
    for (int ks = 0; ks < 3; ks++) Acur[ks] = Anx[ks];
    if (l < NL - 1) {
#pragma unroll
      for (int ks = 0; ks < 3; ks++)
        Anx[ks] = *(const short8*)(wA + ((size_t)((l + 1) * OC + w * 16 + n) * 96) +
                                   ks * 32 + q * 8);
    }
    f32x4 acc[2][2][2];  // [dy][dx][half]
#pragma unroll
    for (int dy = 0; dy < 2; dy++)
#pragma unroll
      for (int dx = 0; dx < 2; dx++)
#pragma unroll
        for (int h = 0; h < 2; h++) acc[dy][dx][h] = f32x4{0.f, 0.f, 0.f, 0.f};

#pragma unroll
    for (int dy = 0; dy < 2; dy++)
#pragma unroll
      for (int dx = 0; dx < 2; dx++)
#pragma unroll
        for (int h = 0; h < 2; h++) {
          int col = 2 * (h * 16 + n) + dx;
          const short* bp = Bm + dy * BSZ + slotbase(col);
#pragma unroll
          for (int ks = 0; ks < 3; ks++) {
            short8 Bf = *(const short8*)(bp + ks * 32 + q * 8);
            acc[dy][dx][h] = __builtin_amdgcn_mfma_f32_16x16x32_bf16(
                Acur[ks], Bf, acc[dy][dx][h], 0, 0, 0);
          }
        }

#pragma unroll
    for (int h = 0; h < 2; h++) {
      short4v sv;
#pragma unroll
      for (int r = 0; r < 4; r++) {
        float v = fmaxf(fmaxf(acc[0][0][h][r], acc[0][1][h][r]),
                        fmaxf(acc[1][0][h][r], acc[1][1][h][r]));
        sv[r] = f2bs(fmaxf(v, 0.f));
      }
      *(short4v*)(&ot[(h * 16 + n) * OTS + w * 16 + q * 4]) = sv;
    }
    __syncthreads();
    {
      int px = t >> 3, seg = t & 7;
      short8 v = *(const short8*)(&ot[px * OTS + seg * 8]);
      *(short8*)(h1t + ((size_t)(l * BATCH + b) * (HP * WP) + py * WP + px) * OC +
                 seg * 8) = v;
    }
    __syncthreads();
  }
}

// ---------------- conv2 via MFMA implicit GEMM + spatial max -> pfeat ----------------
// R19: baseline (R12) dataflow — A-in-registers from global with one-tap prefetch,
// 8 B-reads : 32 MFMA per tap (4-oct A-reuse, proven best MFMA:LDS ratio) — with ONLY
// the staging path replaced by global_load_lds width=16 into the CS2=32 linear slab
// (R15's proven staging: no reg round-trip, no f2bs pass, one vmcnt(0) drain instead
// of per-thread serialized loads; conflicts 2.6M vs baseline CS=40's 7.3M).
// Plus XCD-aware bid swizzle (1024 % 8 == 0, bijective) for wT/h1t L2 locality (R18
// measured FETCH 99->34 MB with swizzle). Register budget unchanged vs baseline
// (~108 arch + 128 acc at launch_bounds(256,2)) -> no spill.
__global__ __launch_bounds__(256, 2) void k_conv2m(
    const short* __restrict__ h1t, const short* __restrict__ wT,
    float* __restrict__ pfeat) {
  constexpr int CS2 = 32;          // shorts per (row,col) slot: 32 ic of chunk (64 B)
  constexpr int RS2 = 36 * CS2;    // 1152 shorts per slab row
  __shared__ alignas(16) short hs[23040];     // 20 rows x 36 cols x 32 ic = 46,080 B
  __shared__ alignas(16) float sred[4][64];
  int raw = blockIdx.x;
  int bid = (raw & 7) * 128 + (raw >> 3);  // XCD swizzle (bijective: 1024/8=128)
  int half = bid & 1;
  int b = (bid >> 1) & 31;
  int l = bid >> 6;
  int t = threadIdx.x;
  int w = t >> 6, lane = t & 63;
  int n = lane & 15, q = lane >> 4;
  int y0 = half * 16;
  const short* hg = h1t + (size_t)(l * BATCH + b) * (HP * WP) * OC;
  const short* wbase = wT + (size_t)l * 25 * OC * OC;

  // per-thread staging source offsets (granule idx = i*256+t < 2880), reused per chunk
  int ofsB[12];
#pragma unroll
  for (int i = 0; i < 12; i++) {
    int idx = i * 256 + t;
    int icq = idx & 3;
    int cc = (idx >> 2) % 36;
    int r = (idx >> 2) / 36;          // < 20 for idx < 2880
    int y = y0 - 2 + r, xx = cc - 2;
    bool ok = (y >= 0) && (y < HP) && (xx >= 0) && (xx < WP);
    ofsB[i] = ok ? ((y * WP + xx) * OC + icq * 8) : -1;
  }

  f32x4 acc[4][8];  // [octile][pxtile: row(4) x colhalf(2)]
#pragma unroll
  for (int i = 0; i < 4; i++)
#pragma unroll
    for (int j = 0; j < 8; j++) acc[i][j] = f32x4{0.f, 0.f, 0.f, 0.f};

  short8 Acur[4], Anext[4];
  // A-frag: A[m=lane&15][k=q*8+j]; k = ic within current 32-chunk
#pragma unroll
  for (int oct = 0; oct < 4; oct++)
    Anext[oct] = *(const short8*)(wbase + (size_t)(oct * 16 + n) * OC + q * 8);

  for (int chunk = 0; chunk < 2; chunk++) {
    __syncthreads();  // protect hs from previous chunk's readers
    // stage: 2880 granules of 16 B via global_load_lds (no dest regs, no VALU pass)
#pragma unroll
    for (int i = 0; i < 12; i++) {
      if (i < 11 || t < 64) {  // idx < 2880 only
        const short* gp = (ofsB[i] < 0) ? zero16 : (hg + ofsB[i] + chunk * 32);
        __builtin_amdgcn_global_load_lds(
            (const __attribute__((address_space(1))) void*)gp,
            (__attribute__((address_space(3))) void*)&hs[(i * 256 + t) * 8],
            16, 0, 0);
      }
    }
    __syncthreads();  // compiler drains vmcnt before the barrier

    for (int tap = 0; tap < 25; tap++) {
#pragma unroll
      for (int i = 0; i < 4; i++) Acur[i] = Anext[i];
      if (!(chunk == 1 && tap == 24)) {
        int ntap = tap + 1, nch = chunk;
        if (ntap == 25) { ntap = 0; nch = 1; }
        const short* tb = wbase + (size_t)ntap * OC * OC;
#pragma unroll
        for (int oct = 0; oct < 4; oct++)
          Anext[oct] = *(const short8*)(tb + (size_t)(oct * 16 + n) * OC +
                                        nch * 32 + q * 8);
      }
      int dy = tap / 5, dx = tap - 5 * dy;
#pragma unroll
      for (int pxt = 0; pxt < 8; pxt++) {
        int lr = 4 * w + (pxt >> 1) + dy;     // slab row 0..19
        int c = (pxt & 1) * 16 + n + dx;      // slab col 0..35
        short8 B = *(const short8*)(&hs[(lr * 36 + c) * CS2 + q * 8]);
#pragma unroll
        for (int oct = 0; oct < 4; oct++)
          acc[oct][pxt] = __builtin_amdgcn_mfma_f32_16x16x32_bf16(
              Acur[oct], B, acc[oct][pxt], 0, 0, 0);
      }
    }
  }

  // epilogue: max over this wave's 128 px; D layout: col(px)=lane&15, row(oc)=q*4+reg
#pragma unroll
  for (int oct = 0; oct < 4; oct++) {
    f32x4 m = acc[oct][0];
#pragma unroll
    for (int pxt = 1; pxt < 8; pxt++)
#pragma unroll
      for (int r = 0; r < 4; r++) m[r] = fmaxf(m[r], acc[oct][pxt][r]);
#pragma unroll
    for (int mask = 1; mask <= 8; mask <<= 1)
#pragma unroll
      for (int r = 0; r < 4; r++) m[r] = fmaxf(m[r], __shfl_xor(m[r], mask, 64));
    if (n == 0) *(f32x4*)&sred[w][oct * 16 + q * 4] = m;
  }
  __syncthreads();
  if (t < 64) {
    float m = fmaxf(fmaxf(sred[0][t], sred[1][t]), fmaxf(sred[2][t], sred[3][t]));
    pfeat[((size_t)(l * BATCH + b) * 2 + half) * OC + t] = m;
  }
}

// ---------------- per-leaf 2-layer MLP; folds half-max + relu ----------------
__global__ __launch_bounds__(128) void k_mlp(
    const float* __restrict__ pfeat, const float* __restrict__ w1s,
    const float* __restrict__ b1s, const float* __restrict__ w2s,
    const float* __restrict__ b2s, float* __restrict__ logits) {
  __shared__ float fs[OC];
  __shared__ float hid[LW];
  int bid = blockIdx.x;
  int b = bid & 31;
  int l = bid >> 5;
  int t = threadIdx.x;
  if (t < OC) {
    const float* pf = pfeat + (size_t)(l * BATCH + b) * 2 * OC;
    fs[t] = fmaxf(fmaxf(pf[t], pf[OC + t]), 0.f);  // relu(global max)
  }
  __syncthreads();
  float h = b1s[l * LW + t];
  for (int c = 0; c < OC; c++)
    h = fmaf(fs[c], w1s[(l * OC + c) * LW + t], h);
  hid[t] = h;
  __syncthreads();
  if (t < OW) {
    float o = b2s[l * OW + t];
    for (int j = 0; j < LW; j++)
      o = fmaf(hid[j], w2s[(l * LW + j) * OW + t], o);
    logits[(size_t)(l * BATCH + b) * OW + t] = o;
  }
}

// ---------------- out[b,o] = sum_l mix[b,l] * logits[l,b,o]  (fp32 out) ----------------
__global__ __launch_bounds__(256) void k_combine(
    const float* __restrict__ logits, const float* __restrict__ mix,
    float* __restrict__ out) {
  int idx = blockIdx.x * 256 + threadIdx.x;
  if (idx >= BATCH * OW) return;
  int b = idx / OW, o = idx - b * OW;
  float s = 0.f;
#pragma unroll
  for (int l = 0; l < NL; l++)
    s = fmaf(mix[b * NL + l], logits[((size_t)l * BATCH + b) * OW + o], s);
  out[idx] = s;
}

extern "C" void kernel_launch(void* const* d_in, const int* in_sizes, int n_in,
                              void* d_out, int out_size, void* d_ws, size_t ws_size,
                              hipStream_t stream) {
  const float* x   = (const float*)d_in[0];
  const float* nw  = (const float*)d_in[1];
  const float* nb  = (const float*)d_in[2];
  const float* cw1 = (const float*)d_in[3];
  const float* cw2 = (const float*)d_in[4];
  const float* w1s = (const float*)d_in[5];
  const float* b1s = (const float*)d_in[6];
  const float* w2s = (const float*)d_in[7];
  const float* b2s = (const float*)d_in[8];
  float* out = (float*)d_out;

  char* ws = (char*)d_ws;
  short* h1t = (short*)ws;  // [l,b][px 1024][ic 64] bf16 = 67.1 MB
  size_t off = (size_t)NL * BATCH * HP * WP * OC * sizeof(short);
  short* wT = (short*)(ws + off); off += (size_t)NL * 25 * OC * OC * sizeof(short);
  short* wA = (short*)(ws + off); off += (size_t)NL * OC * 96 * sizeof(short);
  float* scores_p = (float*)(ws + off); off += 4 * BATCH * 4 * sizeof(float);
  float* mixp   = (float*)(ws + off); off += BATCH * NL * sizeof(float);
  float* pfeat  = (float*)(ws + off); off += (size_t)NL * BATCH * 2 * OC * sizeof(float);
  float* logits = (float*)(ws + off); off += (size_t)NL * BATCH * OW * sizeof(float);
  (void)ws_size; (void)in_sizes; (void)n_in; (void)out_size;

  k_scores<<<4 * BATCH * 4, 256, 0, stream>>>(x, nw, scores_p);
  k_mix<<<1, BATCH * NL, 0, stream>>>(scores_p, nb, mixp);
  k_prep<<<(98304 + 204800) / 256, 256, 0, stream>>>(cw1, cw2, wA, wT);
  k_conv1m<<<BATCH * 32, 256, 0, stream>>>(x, wA, h1t);
  k_conv2m<<<NL * BATCH * 2, 256, 0, stream>>>(h1t, wT, pfeat);
  k_mlp<<<NL * BATCH, 128, 0, stream>>>(pfeat, w1s, b1s, w2s, b2s, logits);
  k_combine<<<(BATCH * OW + 255) / 256, 256, 0, stream>>>(logits, mixp, out);
}

// Round 8
// 200.812 us; speedup vs baseline: 3.7801x; 1.0088x over previous
//
#include <hip/hip_runtime.h>
#include <hip/hip_bf16.h>

using bf16 = __hip_bfloat16;
typedef __attribute__((ext_vector_type(8))) short short8;   // 8 bf16 (4 VGPR)
typedef __attribute__((ext_vector_type(4))) short short4v;  // 4 bf16 (8 B)
typedef __attribute__((ext_vector_type(4))) float f32x4;

constexpr int BATCH = 32;
constexpr int INC = 3;
constexpr int OC = 64;
constexpr int HH = 64;
constexpr int WW = 64;
constexpr int KK = 5;
constexpr int HP = 32;
constexpr int WP = 32;
constexpr int NL = 16;
constexpr int LW = 128;
constexpr int OW = 100;

__device__ __forceinline__ short f2bs(float v) {
  bf16 h = __float2bfloat16(v);
  return *(short*)&h;
}

// 16B zero page: per-lane global source for halo/pad lanes of global_load_lds.
__device__ alignas(16) short zero16[16];

// ---------------- routing scores (partial): conv(x, node_filter) -> 16-row-group max ------
__global__ __launch_bounds__(256) void k_scores(
    const float* __restrict__ x, const float* __restrict__ nw,
    float* __restrict__ scores_p) {
  int bid = blockIdx.x;
  int d = bid & 3;
  int b = (bid >> 2) & 31;
  int g = bid >> 7;  // 0..3: rows 16g..16g+15
  int f = (2 << d) - 2;  // node filter index used at depth d: 0,2,6,14
  __shared__ float wsm[75];
  __shared__ float red[256];
  int t = threadIdx.x;
  if (t < 75) wsm[t] = nw[f * 75 + t];
  __syncthreads();
  float m = -3.0e38f;
  for (int p = g * 1024 + t; p < (g + 1) * 1024; p += 256) {
    int y = p >> 6, xx = p & 63;
    float s = 0.f;
    for (int ic = 0; ic < INC; ic++) {
      for (int ky = 0; ky < KK; ky++) {
        int yy = y + ky - 2;
        if (yy < 0 || yy >= HH) continue;
        const float* xr = x + ((b * INC + ic) * HH + yy) * WW;
        const float* wr = &wsm[(ic * KK + ky) * KK];
        for (int kx = 0; kx < KK; kx++) {
          int xc = xx + kx - 2;
          if (xc < 0 || xc >= WW) continue;
          s = fmaf(xr[xc], wr[kx], s);
        }
      }
    }
    m = fmaxf(m, s);
  }
  red[t] = m;
  __syncthreads();
  for (int s2 = 128; s2 > 0; s2 >>= 1) {
    if (t < s2) red[t] = fmaxf(red[t], red[t + s2]);
    __syncthreads();
  }
  if (t == 0) scores_p[(d * BATCH + b) * 4 + g] = red[0];
}

// ---------------- soft-routing mixture over the binary tree ----------------
__global__ void k_mix(const float* __restrict__ scores_p,
                      const float* __restrict__ nb, float* __restrict__ mix) {
  int t = threadIdx.x;
  int b = t >> 4, l = t & 15;
  float m = 1.f;
#pragma unroll
  for (int d = 0; d < 4; d++) {
    const float* sp = scores_p + (d * BATCH + b) * 4;
    float sc = fmaxf(fmaxf(sp[0], sp[1]), fmaxf(sp[2], sp[3]));
    int j = l >> (3 - d);
    int i = j >> 1;
    int bit = j & 1;
    float z = sc + nb[(1 << d) - 1 + i];
    float be = 1.f / (1.f + expf(-z));
    m *= bit ? be : (1.f - be);
  }
  mix[b * NL + l] = m;
}

// ---------------- merged weight prep ----------------
__global__ __launch_bounds__(256) void k_prep(
    const float* __restrict__ cw1, const float* __restrict__ cw2,
    short* __restrict__ wA, short* __restrict__ wT) {
  int idx = blockIdx.x * 256 + threadIdx.x;
  if (idx < 98304) {
    int k = idx % 96;
    int rem = idx / 96;  // l*64 + oc
    float v = (k < 75) ? cw1[(size_t)rem * 75 + k] : 0.f;
    wA[(size_t)rem * 96 + k] = f2bs(v);
  } else {
    int i2 = idx - 98304;  // < 204800
    int icq = i2 & 7;
    int oc = (i2 >> 3) & 63;
    int rem = i2 >> 9;  // l*25 + tap
    short8 v;
#pragma unroll
    for (int j = 0; j < 8; j++) {
      int ic = icq * 8 + j;
      int l = rem / 25, tap = rem % 25;
      v[j] = f2bs(cw2[((size_t)(l * OC + oc) * OC + ic) * 25 + tap]);
    }
    *(short8*)(wT + ((size_t)rem * OC + oc) * OC + icq * 8) = v;
  }
}

// ---------------- conv1 via im2col + MFMA + in-register maxpool/relu -> h1t ----------------
// (R8/R12 version verbatim — known-good on hardware)
__device__ __forceinline__ int slotbase(int col) {
  return col * 104 + 8 * ((-(col >> 1)) & 7);
}

__global__ __launch_bounds__(256) void k_conv1m(
    const float* __restrict__ x, const short* __restrict__ wA,
    short* __restrict__ h1t) {
  constexpr int BSZ = 64 * 104 + 64;
  constexpr int OTS = 72;
  __shared__ alignas(16) short Bm[2 * BSZ];
  __shared__ alignas(16) short ot[32 * OTS];
  int bid = blockIdx.x;
  int py = bid & 31;
  int b = bid >> 5;
  int t = threadIdx.x;
  int w = t >> 6, lane = t & 63;
  int n = lane & 15, q = lane >> 4;

  for (int i = t; i < BSZ; i += 256) ((int*)Bm)[i] = 0;
  __syncthreads();
  for (int i = t; i < 1200; i += 256) {
    int cg = i & 7;
    int kk = (i >> 3) % 75;
    int dy = (i >> 3) / 75;
    int ic = kk / 25, r25 = kk % 25;
    int ky = r25 / 5, kx = r25 % 5;
    int y = 2 * py + dy + ky - 2;
    const float* xr = x + ((size_t)(b * INC + ic) * HH + y) * WW;
    short* dst = Bm + dy * BSZ;
#pragma unroll
    for (int c8 = 0; c8 < 8; c8++) {
      int c = cg * 8 + c8;
      int cx = c + kx - 2;
      float v = 0.f;
      if (y >= 0 && y < HH && cx >= 0 && cx < WW) v = xr[cx];
      dst[slotbase(c) + kk] = f2bs(v);
    }
  }
  __syncthreads();

  short8 Acur[3], Anx[3];
#pragma unroll
  for (int ks = 0; ks < 3; ks++)
    Anx[ks] = *(const short8*)(wA + ((size_t)(w * 16 + n) * 96) + ks * 32 + q * 8);

  for (int l = 0; l < NL; l++) {
#pragma unroll
    for (int ks = 0; ks < 3; ks++) Acur[ks] = Anx[ks];
    if (l < NL - 1) {
#pragma unroll
      for (int ks = 0; ks < 3; ks++)
        Anx[ks] = *(const short8*)(wA + ((size_t)((l + 1) * OC + w * 16 + n) * 96) +
                                   ks * 32 + q * 8);
    }
    f32x4 acc[2][2][2];  // [dy][dx][half]
#pragma unroll
    for (int dy = 0; dy < 2; dy++)
#pragma unroll
      for (int dx = 0; dx < 2; dx++)
#pragma unroll
        for (int h = 0; h < 2; h++) acc[dy][dx][h] = f32x4{0.f, 0.f, 0.f, 0.f};

#pragma unroll
    for (int dy = 0; dy < 2; dy++)
#pragma unroll
      for (int dx = 0; dx < 2; dx++)
#pragma unroll
        for (int h = 0; h < 2; h++) {
          int col = 2 * (h * 16 + n) + dx;
          const short* bp = Bm + dy * BSZ + slotbase(col);
#pragma unroll
          for (int ks = 0; ks < 3; ks++) {
            short8 Bf = *(const short8*)(bp + ks * 32 + q * 8);
            acc[dy][dx][h] = __builtin_amdgcn_mfma_f32_16x16x32_bf16(
                Acur[ks], Bf, acc[dy][dx][h], 0, 0, 0);
          }
        }

#pragma unroll
    for (int h = 0; h < 2; h++) {
      short4v sv;
#pragma unroll
      for (int r = 0; r < 4; r++) {
        float v = fmaxf(fmaxf(acc[0][0][h][r], acc[0][1][h][r]),
                        fmaxf(acc[1][0][h][r], acc[1][1][h][r]));
        sv[r] = f2bs(fmaxf(v, 0.f));
      }
      *(short4v*)(&ot[(h * 16 + n) * OTS + w * 16 + q * 4]) = sv;
    }
    __syncthreads();
    {
      int px = t >> 3, seg = t & 7;
      short8 v = *(const short8*)(&ot[px * OTS + seg * 8]);
      *(short8*)(h1t + ((size_t)(l * BATCH + b) * (HP * WP) + py * WP + px) * OC +
                 seg * 8) = v;
    }
    __syncthreads();
  }
}

// ---------------- conv2 via MFMA implicit GEMM + spatial max -> pfeat ----------------
// R20 = R19 + two changes:
// (a) q-rotation LDS swizzle (both-sides, rule #21): within each 64B (slot) the
//     16B granule v holds icq = (v - (c>>1)) & 3. gload_lds dest stays LINEAR;
//     the permutation is applied to the per-lane GLOBAL SOURCE (staging) and to
//     the read address v = (q + (c>>1)) & 3 (compute). For a ds_read_b128 at
//     fixed q, consecutive c now cover all 8 bank-groups evenly -> 2 lanes/bank
//     (free, m136). R19 measured ~4 extra cy/read (6.55M conflicts) without this.
// (b) s_setprio(1) around the per-tap MFMA burst (T5): waves drift across taps
//     within a chunk (no per-tap barrier) -> role diversity exists.
__global__ __launch_bounds__(256, 2) void k_conv2m(
    const short* __restrict__ h1t, const short* __restrict__ wT,
    float* __restrict__ pfeat) {
  constexpr int CS2 = 32;          // shorts per (row,col) slot: 32 ic of chunk (64 B)
  __shared__ alignas(16) short hs[23040];     // 20 rows x 36 cols x 32 ic = 46,080 B
  __shared__ alignas(16) float sred[4][64];
  int raw = blockIdx.x;
  int bid = (raw & 7) * 128 + (raw >> 3);  // XCD swizzle (bijective: 1024/8=128)
  int half = bid & 1;
  int b = (bid >> 1) & 31;
  int l = bid >> 6;
  int t = threadIdx.x;
  int w = t >> 6, lane = t & 63;
  int n = lane & 15, q = lane >> 4;
  int y0 = half * 16;
  const short* hg = h1t + (size_t)(l * BATCH + b) * (HP * WP) * OC;
  const short* wbase = wT + (size_t)l * 25 * OC * OC;

  // per-thread staging source offsets (granule idx = i*256+t < 2880), reused per chunk.
  // Swizzle: granule (slot, v) sources icq = (v - (cc>>1)) & 3.
  int ofsB[12];
#pragma unroll
  for (int i = 0; i < 12; i++) {
    int idx = i * 256 + t;
    int v = idx & 3;
    int cc = (idx >> 2) % 36;
    int r = (idx >> 2) / 36;          // < 20 for idx < 2880
    int icq = (v - (cc >> 1)) & 3;
    int y = y0 - 2 + r, xx = cc - 2;
    bool ok = (y >= 0) && (y < HP) && (xx >= 0) && (xx < WP);
    ofsB[i] = ok ? ((y * WP + xx) * OC + icq * 8) : -1;
  }

  f32x4 acc[4][8];  // [octile][pxtile: row(4) x colhalf(2)]
#pragma unroll
  for (int i = 0; i < 4; i++)
#pragma unroll
    for (int j = 0; j < 8; j++) acc[i][j] = f32x4{0.f, 0.f, 0.f, 0.f};

  short8 Acur[4], Anext[4];
  // A-frag: A[m=lane&15][k=q*8+j]; k = ic within current 32-chunk
#pragma unroll
  for (int oct = 0; oct < 4; oct++)
    Anext[oct] = *(const short8*)(wbase + (size_t)(oct * 16 + n) * OC + q * 8);

  for (int chunk = 0; chunk < 2; chunk++) {
    __syncthreads();  // protect hs from previous chunk's readers
    // stage: 2880 granules of 16 B via global_load_lds (linear dest, swizzled source)
#pragma unroll
    for (int i = 0; i < 12; i++) {
      if (i < 11 || t < 64) {  // idx < 2880 only
        const short* gp = (ofsB[i] < 0) ? zero16 : (hg + ofsB[i] + chunk * 32);
        __builtin_amdgcn_global_load_lds(
            (const __attribute__((address_space(1))) void*)gp,
            (__attribute__((address_space(3))) void*)&hs[(i * 256 + t) * 8],
            16, 0, 0);
      }
    }
    __syncthreads();  // compiler drains vmcnt before the barrier

    for (int tap = 0; tap < 25; tap++) {
#pragma unroll
      for (int i = 0; i < 4; i++) Acur[i] = Anext[i];
      if (!(chunk == 1 && tap == 24)) {
        int ntap = tap + 1, nch = chunk;
        if (ntap == 25) { ntap = 0; nch = 1; }
        const short* tb = wbase + (size_t)ntap * OC * OC;
#pragma unroll
        for (int oct = 0; oct < 4; oct++)
          Anext[oct] = *(const short8*)(tb + (size_t)(oct * 16 + n) * OC +
                                        nch * 32 + q * 8);
      }
      int dy = tap / 5, dx = tap - 5 * dy;
      __builtin_amdgcn_s_setprio(1);
#pragma unroll
      for (int pxt = 0; pxt < 8; pxt++) {
        int lr = 4 * w + (pxt >> 1) + dy;     // slab row 0..19
        int c = (pxt & 1) * 16 + n + dx;      // slab col 0..35
        int v = (q + (c >> 1)) & 3;           // swizzled granule within slot
        short8 B = *(const short8*)(&hs[(lr * 36 + c) * CS2 + v * 8]);
#pragma unroll
        for (int oct = 0; oct < 4; oct++)
          acc[oct][pxt] = __builtin_amdgcn_mfma_f32_16x16x32_bf16(
              Acur[oct], B, acc[oct][pxt], 0, 0, 0);
      }
      __builtin_amdgcn_s_setprio(0);
    }
  }

  // epilogue: max over this wave's 128 px; D layout: col(px)=lane&15, row(oc)=q*4+reg
#pragma unroll
  for (int oct = 0; oct < 4; oct++) {
    f32x4 m = acc[oct][0];
#pragma unroll
    for (int pxt = 1; pxt < 8; pxt++)
#pragma unroll
      for (int r = 0; r < 4; r++) m[r] = fmaxf(m[r], acc[oct][pxt][r]);
#pragma unroll
    for (int mask = 1; mask <= 8; mask <<= 1)
#pragma unroll
      for (int r = 0; r < 4; r++) m[r] = fmaxf(m[r], __shfl_xor(m[r], mask, 64));
    if (n == 0) *(f32x4*)&sred[w][oct * 16 + q * 4] = m;
  }
  __syncthreads();
  if (t < 64) {
    float m = fmaxf(fmaxf(sred[0][t], sred[1][t]), fmaxf(sred[2][t], sred[3][t]));
    pfeat[((size_t)(l * BATCH + b) * 2 + half) * OC + t] = m;
  }
}

// ---------------- per-leaf 2-layer MLP; folds half-max + relu ----------------
__global__ __launch_bounds__(128) void k_mlp(
    const float* __restrict__ pfeat, const float* __restrict__ w1s,
    const float* __restrict__ b1s, const float* __restrict__ w2s,
    const float* __restrict__ b2s, float* __restrict__ logits) {
  __shared__ float fs[OC];
  __shared__ float hid[LW];
  int bid = blockIdx.x;
  int b = bid & 31;
  int l = bid >> 5;
  int t = threadIdx.x;
  if (t < OC) {
    const float* pf = pfeat + (size_t)(l * BATCH + b) * 2 * OC;
    fs[t] = fmaxf(fmaxf(pf[t], pf[OC + t]), 0.f);  // relu(global max)
  }
  __syncthreads();
  float h = b1s[l * LW + t];
  for (int c = 0; c < OC; c++)
    h = fmaf(fs[c], w1s[(l * OC + c) * LW + t], h);
  hid[t] = h;
  __syncthreads();
  if (t < OW) {
    float o = b2s[l * OW + t];
    for (int j = 0; j < LW; j++)
      o = fmaf(hid[j], w2s[(l * LW + j) * OW + t], o);
    logits[(size_t)(l * BATCH + b) * OW + t] = o;
  }
}

// ---------------- out[b,o] = sum_l mix[b,l] * logits[l,b,o]  (fp32 out) ----------------
__global__ __launch_bounds__(256) void k_combine(
    const float* __restrict__ logits, const float* __restrict__ mix,
    float* __restrict__ out) {
  int idx = blockIdx.x * 256 + threadIdx.x;
  if (idx >= BATCH * OW) return;
  int b = idx / OW, o = idx - b * OW;
  float s = 0.f;
#pragma unroll
  for (int l = 0; l < NL; l++)
    s = fmaf(mix[b * NL + l], logits[((size_t)l * BATCH + b) * OW + o], s);
  out[idx] = s;
}

extern "C" void kernel_launch(void* const* d_in, const int* in_sizes, int n_in,
                              void* d_out, int out_size, void* d_ws, size_t ws_size,
                              hipStream_t stream) {
  const float* x   = (const float*)d_in[0];
  const float* nw  = (const float*)d_in[1];
  const float* nb  = (const float*)d_in[2];
  const float* cw1 = (const float*)d_in[3];
  const float* cw2 = (const float*)d_in[4];
  const float* w1s = (const float*)d_in[5];
  const float* b1s = (const float*)d_in[6];
  const float* w2s = (const float*)d_in[7];
  const float* b2s = (const float*)d_in[8];
  float* out = (float*)d_out;

  char* ws = (char*)d_ws;
  short* h1t = (short*)ws;  // [l,b][px 1024][ic 64] bf16 = 67.1 MB
  size_t off = (size_t)NL * BATCH * HP * WP * OC * sizeof(short);
  short* wT = (short*)(ws + off); off += (size_t)NL * 25 * OC * OC * sizeof(short);
  short* wA = (short*)(ws + off); off += (size_t)NL * OC * 96 * sizeof(short);
  float* scores_p = (float*)(ws + off); off += 4 * BATCH * 4 * sizeof(float);
  float* mixp   = (float*)(ws + off); off += BATCH * NL * sizeof(float);
  float* pfeat  = (float*)(ws + off); off += (size_t)NL * BATCH * 2 * OC * sizeof(float);
  float* logits = (float*)(ws + off); off += (size_t)NL * BATCH * OW * sizeof(float);
  (void)ws_size; (void)in_sizes; (void)n_in; (void)out_size;

  k_scores<<<4 * BATCH * 4, 256, 0, stream>>>(x, nw, scores_p);
  k_mix<<<1, BATCH * NL, 0, stream>>>(scores_p, nb, mixp);
  k_prep<<<(98304 + 204800) / 256, 256, 0, stream>>>(cw1, cw2, wA, wT);
  k_conv1m<<<BATCH * 32, 256, 0, stream>>>(x, wA, h1t);
  k_conv2m<<<NL * BATCH * 2, 256, 0, stream>>>(h1t, wT, pfeat);
  k_mlp<<<NL * BATCH, 128, 0, stream>>>(pfeat, w1s, b1s, w2s, b2s, logits);
  k_combine<<<(BATCH * OW + 255) / 256, 256, 0, stream>>>(logits, mixp, out);
}